// Round 3
// baseline (290.079 us; speedup 1.0000x reference)
//
#include <hip/hip_runtime.h>
#include <hip/hip_fp16.h>

// B=4, L=2048, D=1024.  All GEMMs fp16-MFMA (f32 accum), 8-phase 256xBN
// tiles, BK=64, 8 waves (2M x 4N), counted-vmcnt pipeline (T3+T4), setprio
// (T5), conflict-free [kg][row][8] LDS layout (T2-equivalent), XCD swizzle.
//  cvt: X, Wkqv, Wproj -> fp16
//  G1 (BN=256): kqvh = f16(Xh @ Wkqvh^T + bkqv)            8192x3072
//  G2 (BN=256): S[b] = Qh@Kh^T * 1/32, mask, skip masked col-tiles (f32)
//  SM:  masked row softmax -> attn f16
//  G4 (BN=128): out2h = f16(perm(attn @ V)), K limited to ceil(vlen/64)
//  G5 (BN=128): out = out2h @ Wprojh^T + bproj (f32)

typedef _Float16 f16;
typedef _Float16 f16x4 __attribute__((ext_vector_type(4)));
typedef _Float16 f16x8 __attribute__((ext_vector_type(8)));
typedef float f32x4 __attribute__((ext_vector_type(4)));

__device__ __forceinline__ void gload16(const f16* g, f16* l) {
  __builtin_amdgcn_global_load_lds(
      (const __attribute__((address_space(1))) unsigned int*)g,
      (__attribute__((address_space(3))) unsigned int*)l, 16, 0, 0);
}

#define BARX() __builtin_amdgcn_s_barrier()
#define LGKM0()                                         \
  {                                                     \
    asm volatile("s_waitcnt lgkmcnt(0)" ::: "memory"); \
    __builtin_amdgcn_sched_barrier(0);                  \
  }
#define ASM_VMCNT(N) asm volatile("s_waitcnt vmcnt(" #N ")" ::: "memory")

// ---- staging macros (per wave: w = kg plane) ----
#define STAGE_A(slot, half, t)                                              \
  {                                                                         \
    const int kt_ = (t) << 6;                                               \
    _Pragma("unroll") for (int c_ = 0; c_ < 2; ++c_)                        \
        gload16(A + (long)(m0 + (half)*128 + c_ * 64 + ln) * lda + kt_ +    \
                    w * 8,                                                  \
                &As[(slot)*16384 + (half)*8192 + w * 1024 + c_ * 512]);     \
  }

#define STAGE_B(slot, half, t)                                              \
  {                                                                         \
    const int kt_ = (t) << 6;                                               \
    if constexpr (BN == 256) {                                              \
      _Pragma("unroll") for (int c_ = 0; c_ < 2; ++c_)                      \
          gload16(Bp + (long)(n0 + (half)*128 + c_ * 64 + ln) * ldb + kt_ + \
                      w * 8,                                                \
                  &Bs[(slot)*16384 + (half)*8192 + w * 1024 + c_ * 512]);   \
    } else {                                                                \
      gload16(Bp + (long)(n0 + (half)*64 + ln) * ldb + kt_ + w * 8,         \
              &Bs[(slot)*8192 + (half)*4096 + w * 512]);                    \
    }                                                                       \
  }

#define READ_A_HALF(slot, ih)                                             \
  _Pragma("unroll") for (int i_ = 0; i_ < 4; ++i_)                        \
      _Pragma("unroll") for (int ks_ = 0; ks_ < 2; ++ks_)                 \
          af[(ih)*4 + i_][ks_] = *(const f16x8*)&As[(slot)*16384 +        \
                                                    ahalf * 8192 +        \
                                                    (ks_ * 4 + lq) * 1024 + \
                                                    (((ih)*4 + i_) * 16 + lc) * 8];

#define READ_B_HALF(slot, jh)                                                  \
  _Pragma("unroll") for (int j_ = 0; j_ < JQ; ++j_)                            \
      _Pragma("unroll") for (int ks_ = 0; ks_ < 2; ++ks_) {                    \
    if constexpr (BT) {                                                        \
      bf[(jh)*JQ + j_][ks_] =                                                  \
          *(const f16x8*)&Bs[(slot)*8256 + (ks_ * 4 + lq) * 1032 +             \
                             (wn + ((jh)*JQ + j_) * 16 + lc) * 8];             \
    } else if constexpr (BN == 256) {                                          \
      bf[(jh)*JQ + j_][ks_] =                                                  \
          *(const f16x8*)&Bs[(slot)*16384 + bhalf * 8192 +                     \
                             (ks_ * 4 + lq) * 1024 +                           \
                             (bcol0 + ((jh)*JQ + j_) * 16 + lc) * 8];          \
    } else {                                                                   \
      bf[(jh)*JQ + j_][ks_] =                                                  \
          *(const f16x8*)&Bs[(slot)*8192 + bhalf * 4096 +                      \
                             (ks_ * 4 + lq) * 512 +                            \
                             (bcol0 + ((jh)*JQ + j_) * 16 + lc) * 8];          \
    }                                                                          \
  }

#define QUAD(qi, qj)                                                          \
  _Pragma("unroll") for (int i_ = 0; i_ < 4; ++i_)                            \
      _Pragma("unroll") for (int j_ = 0; j_ < JQ; ++j_)                       \
          _Pragma("unroll") for (int ks_ = 0; ks_ < 2; ++ks_)                 \
              acc[(qi)*4 + i_][(qj)*JQ + j_] =                                \
                  __builtin_amdgcn_mfma_f32_16x16x32_f16(                     \
                      af[(qi)*4 + i_][ks_], bf[(qj)*JQ + j_][ks_],            \
                      acc[(qi)*4 + i_][(qj)*JQ + j_], 0, 0, 0);

#define LOAD_V(t, ra, rb)                                                  \
  {                                                                        \
    const f16* p_ = Bp + (long)(((t) << 6) + 2 * kp) * ldb + n0 + cg * 8; \
    ra = *(const uint4*)p_;                                                \
    rb = *(const uint4*)(p_ + ldb);                                        \
  }

#define WRITE_V(slot, ra, rb)                                              \
  {                                                                        \
    unsigned* bw_ = (unsigned*)Bs + (slot)*4128 + (kp >> 2) * 516 +        \
                    (kp & 3);                                              \
    const unsigned a_[4] = {ra.x, ra.y, ra.z, ra.w};                       \
    const unsigned b_[4] = {rb.x, rb.y, rb.z, rb.w};                       \
    _Pragma("unroll") for (int j_ = 0; j_ < 4; ++j_) {                     \
      bw_[(cg * 8 + 2 * j_) * 4] = (a_[j_] & 0xffffu) | (b_[j_] << 16);    \
      bw_[(cg * 8 + 2 * j_ + 1) * 4] =                                     \
          (a_[j_] >> 16) | (b_[j_] & 0xffff0000u);                         \
    }                                                                      \
  }

template <int BN, bool BT, bool BIAS, bool MASK, bool PERM, bool OUTF16,
          bool KLIM>
__global__ __launch_bounds__(512, 2) void gemm8p(
    const f16* __restrict__ A, long lda, const f16* __restrict__ Bp, long ldb,
    void* __restrict__ Cv, long ldc, const float* __restrict__ bias,
    const int* __restrict__ valid_lens, float scale, int K, long strideA,
    long strideB, long strideC) {
  constexpr int NR = BN / 64;   // B frags per wave
  constexpr int JQ = NR / 2;    // frags per quadrant
  __shared__ __align__(16) f16 As[32768];
  __shared__ __align__(16) f16 Bs[BT ? 16512 : (BN == 256 ? 32768 : 16384)];

  const int tid = threadIdx.x;
  const int w = tid >> 6;
  const int ln = tid & 63;
  const int bz = blockIdx.z;

  // XCD-aware bijective swizzle (m204)
  const int gx = gridDim.x, nwg = gx * gridDim.y;
  int lin = blockIdx.y * gx + blockIdx.x;
  {
    const int xcd = lin & 7, rest = lin >> 3;
    const int q = nwg >> 3, r = nwg & 7;
    lin = ((xcd < r) ? xcd * (q + 1) : r * (q + 1) + (xcd - r) * q) + rest;
  }
  const int n0 = (lin % gx) * BN;
  const int m0 = (lin / gx) * 256;

  const int vlen = (MASK || KLIM) ? valid_lens[bz] : 0;
  if (MASK && n0 >= vlen) return;

  A += (long)bz * strideA;
  Bp += (long)bz * strideB;

  int nk = K >> 6;
  if (KLIM) {
    int t = (vlen + 63) >> 6;
    nk = t < nk ? t : nk;
  }

  const int lq = ln >> 4, lc = ln & 15;
  const int ahalf = w >> 2;
  const int bhalf = (w & 3) >> 1;
  const int bcol0 = ((w & 3) & 1) * (BN == 256 ? 64 : 32);
  const int wn = (w & 3) * (BN / 4);
  const int kp = tid & 31, cg = tid >> 5;  // BT staging

  f16x8 af[8][2], bf[NR][2];
  f32x4 acc[8][NR];
#pragma unroll
  for (int i = 0; i < 8; ++i)
#pragma unroll
    for (int j = 0; j < NR; ++j) acc[i][j] = (f32x4){0.f, 0.f, 0.f, 0.f};

  uint4 va0, va1, vb0, vb1;

  // ---- prologue: stage tile 0 (+ tile 1 partial) ----
  if constexpr (!BT) {
    STAGE_A(0, 0, 0); STAGE_A(0, 1, 0); STAGE_B(0, 0, 0); STAGE_B(0, 1, 0);
    if (nk > 1) {
      STAGE_A(1, 0, 1); STAGE_A(1, 1, 1); STAGE_B(1, 0, 1);
      if constexpr (BN == 256) ASM_VMCNT(6); else ASM_VMCNT(5);
    } else {
      ASM_VMCNT(0);
    }
    __builtin_amdgcn_sched_barrier(0);
  } else {
    LOAD_V(0, va0, va1);
    if (nk > 1) LOAD_V(1, vb0, vb1);
    STAGE_A(0, 0, 0); STAGE_A(0, 1, 0);
    if (nk > 1) { STAGE_A(1, 0, 1); STAGE_A(1, 1, 1); }
    WRITE_V(0, va0, va1);
    if (nk > 1) WRITE_V(1, vb0, vb1);
    if (nk > 1) ASM_VMCNT(4); else ASM_VMCNT(0);
    __builtin_amdgcn_sched_barrier(0);
    LGKM0();
  }
  BARX();

  // ---- main loop: 4 phases per K-tile, 2-deep prefetch ----
  for (int t = 0; t < nk; ++t) {
    const int s = t & 1;
    const int sn = s ^ 1;
    const bool p1 = (t + 1) < nk;
    const bool p2 = (t + 2) < nk;

    // PH1: A rows 0-63(frag), B first col-half; stage B1(t+1) / load V(t+2)
    READ_A_HALF(s, 0);
    READ_B_HALF(s, 0);
    if constexpr (BT) {
      if (p2) LOAD_V(t + 2, va0, va1);
    } else {
      if (p1) STAGE_B(sn, 1, t + 1);
    }
    BARX(); LGKM0();
    __builtin_amdgcn_s_setprio(1); QUAD(0, 0); __builtin_amdgcn_s_setprio(0);
    BARX();

    // PH2: A rows 64-127
    READ_A_HALF(s, 1);
    BARX(); LGKM0();
    __builtin_amdgcn_s_setprio(1); QUAD(1, 0); __builtin_amdgcn_s_setprio(0);
    BARX();

    // PH3: B second col-half; stage A0(t+2)
    READ_B_HALF(s, 1);
    if (p2) STAGE_A(s, 0, t + 2);
    BARX(); LGKM0();
    __builtin_amdgcn_s_setprio(1); QUAD(0, 1); __builtin_amdgcn_s_setprio(0);
    BARX();

    // PH4: stage A1(t+2) + B0(t+2)/write V(t+2); boundary vmcnt
    if (p2) {
      STAGE_A(s, 1, t + 2);
      if constexpr (!BT) { STAGE_B(s, 0, t + 2); }
      else { WRITE_V(s, va0, va1); }
    }
    BARX(); LGKM0();
    __builtin_amdgcn_s_setprio(1); QUAD(1, 1); __builtin_amdgcn_s_setprio(0);
    if (p2) {
      if constexpr (BT) ASM_VMCNT(4);
      else if constexpr (BN == 256) ASM_VMCNT(6);
      else ASM_VMCNT(5);
    } else {
      ASM_VMCNT(0);
    }
    __builtin_amdgcn_sched_barrier(0);
    BARX();
  }

  // ---- epilogue ----
  const int wm = ahalf * 128;
#pragma unroll
  for (int i = 0; i < 8; ++i) {
#pragma unroll
    for (int j = 0; j < NR; ++j) {
      const int col = n0 + wn + j * 16 + lc;
      const float bv = BIAS ? bias[col] : 0.f;
      if constexpr (PERM) {
        const int row0 = m0 + wm + i * 16 + lq * 4;
        f16x4 pk;
#pragma unroll
        for (int r = 0; r < 4; ++r) pk[r] = (f16)acc[i][j][r];
        const long idx =
            ((long)bz * 2048 + 2 * col + (row0 >> 10)) * 1024 + (row0 & 1023);
        *(f16x4*)&((f16*)Cv)[idx] = pk;
      } else {
#pragma unroll
        for (int r = 0; r < 4; ++r) {
          const int row = m0 + wm + i * 16 + lq * 4 + r;
          float c = acc[i][j][r];
          if (MASK) c = (col >= vlen) ? -1000000.0f : c * scale;
          if (BIAS) c += bv;
          const long idx = (long)bz * strideC + (long)row * ldc + col;
          if constexpr (OUTF16)
            ((f16*)Cv)[idx] = (f16)c;
          else
            ((float*)Cv)[idx] = c;
        }
      }
    }
  }
}

__global__ __launch_bounds__(256) void softmax_rows(
    const float* __restrict__ S, f16* __restrict__ attn,
    const int* __restrict__ vlens) {
  const long row = blockIdx.x;
  const int b = (int)(row >> 11);
  const int vlen = vlens[b];
  const float* p = S + row * 2048;
  const int tid = threadIdx.x;
  const int wave = tid >> 6, lane = tid & 63;
  const int c0 = tid * 8;

  float v[8];
  if (c0 + 8 <= vlen) {
    const float4 a = *(const float4*)(p + c0);
    const float4 bq = *(const float4*)(p + c0 + 4);
    v[0] = a.x; v[1] = a.y; v[2] = a.z; v[3] = a.w;
    v[4] = bq.x; v[5] = bq.y; v[6] = bq.z; v[7] = bq.w;
  } else {
#pragma unroll
    for (int j = 0; j < 8; ++j)
      v[j] = (c0 + j < vlen) ? p[c0 + j] : -1000000.0f;
  }

  float mx = v[0];
#pragma unroll
  for (int j = 1; j < 8; ++j) mx = fmaxf(mx, v[j]);
#pragma unroll
  for (int o = 1; o < 64; o <<= 1) mx = fmaxf(mx, __shfl_xor(mx, o));
  __shared__ float redm[4];
  if (lane == 0) redm[wave] = mx;
  __syncthreads();
  mx = fmaxf(fmaxf(redm[0], redm[1]), fmaxf(redm[2], redm[3]));

  float s = 0.f;
#pragma unroll
  for (int j = 0; j < 8; ++j) {
    v[j] = __expf(v[j] - mx);
    s += v[j];
  }
#pragma unroll
  for (int o = 1; o < 64; o <<= 1) s += __shfl_xor(s, o);
  __shared__ float reds[4];
  if (lane == 0) reds[wave] = s;
  __syncthreads();
  s = reds[0] + reds[1] + reds[2] + reds[3];

  const float inv = 1.0f / s;
  f16x8 ov;
#pragma unroll
  for (int j = 0; j < 8; ++j) ov[j] = (f16)(v[j] * inv);
  *(f16x8*)(attn + row * 2048 + c0) = ov;
}

__global__ __launch_bounds__(256) void cvt_f32_f16(const float* __restrict__ s,
                                                   f16* __restrict__ d, int n) {
  const int i = (blockIdx.x * 256 + threadIdx.x) * 8;
  if (i >= n) return;
  const float4 a = *(const float4*)(s + i);
  const float4 b = *(const float4*)(s + i + 4);
  f16x8 o;
  o[0] = (f16)a.x; o[1] = (f16)a.y; o[2] = (f16)a.z; o[3] = (f16)a.w;
  o[4] = (f16)b.x; o[5] = (f16)b.y; o[6] = (f16)b.z; o[7] = (f16)b.w;
  *(f16x8*)(d + i) = o;
}

extern "C" void kernel_launch(void* const* d_in, const int* in_sizes, int n_in,
                              void* d_out, int out_size, void* d_ws,
                              size_t ws_size, hipStream_t stream) {
  const float* X = (const float*)d_in[0];
  const int* vlens = (const int*)d_in[1];
  const float* Wkqv = (const float*)d_in[2];
  const float* bkqv = (const float*)d_in[3];
  const float* Wproj = (const float*)d_in[4];
  const float* bproj = (const float*)d_in[5];
  float* out = (float*)d_out;

  char* w = (char*)d_ws;
  f16* Xh = (f16*)w;      w += 8192L * 1024 * 2;
  f16* Wkqvh = (f16*)w;   w += 3072L * 1024 * 2;
  f16* Wprojh = (f16*)w;  w += 1024L * 1024 * 2;
  f16* kqvh = (f16*)w;    w += 8192L * 3072 * 2;
  f16* attnh = (f16*)w;   w += 4L * 2048 * 2048 * 2;
  f16* out2h = (f16*)w;   w += 8192L * 1024 * 2;
  float* S = (float*)w;

  cvt_f32_f16<<<4096, 256, 0, stream>>>(X, Xh, 8192 * 1024);
  cvt_f32_f16<<<1536, 256, 0, stream>>>(Wkqv, Wkqvh, 3072 * 1024);
  cvt_f32_f16<<<512, 256, 0, stream>>>(Wproj, Wprojh, 1024 * 1024);

  // G1: kqvh = f16(Xh @ Wkqvh^T + bkqv)   M=8192 N=3072 K=1024
  gemm8p<256, false, true, false, false, true, false>
      <<<dim3(12, 32, 1), 512, 0, stream>>>(Xh, 1024, Wkqvh, 1024, kqvh, 3072,
                                            bkqv, nullptr, 1.0f, 1024, 0, 0, 0);

  // G2: S[b] = Qh @ Kh^T * 1/32, masked   M=N=2048 K=1024
  gemm8p<256, false, false, true, false, false, false>
      <<<dim3(8, 8, 4), 512, 0, stream>>>(
          kqvh + 1024, 3072, kqvh, 3072, S, 2048, nullptr, vlens, 0.03125f,
          1024, 2048L * 3072, 2048L * 3072, 2048L * 2048);

  // SM: masked softmax rows -> fp16 attn
  softmax_rows<<<8192, 256, 0, stream>>>(S, attnh, vlens);

  // G4: out2h = f16(perm(attn @ V))   M=2048 N=1024 K<=2048 (vlen-limited)
  gemm8p<128, true, false, false, true, true, true>
      <<<dim3(8, 8, 4), 512, 0, stream>>>(
          attnh, 2048, kqvh + 2048, 3072, out2h, 1024, nullptr, vlens, 1.0f,
          2048, 2048L * 2048, 2048L * 3072, 2048L * 1024);

  // G5: out = out2h @ Wprojh^T + bproj   M=8192 N=1024 K=1024 (f32 out)
  gemm8p<128, false, true, false, false, false, false>
      <<<dim3(8, 32, 1), 512, 0, stream>>>(out2h, 1024, Wprojh, 1024, out,
                                           1024, bproj, nullptr, 1.0f, 1024, 0,
                                           0, 0);
}

// Round 5
// 256.095 us; speedup vs baseline: 1.1327x; 1.1327x over previous
//
#include <hip/hip_runtime.h>
#include <hip/hip_fp16.h>

// B=4, L=2048, D=1024.
//  cvt: X, Wkqv, Wproj -> fp16
//  G1 (8-phase 256x256): kqvh = f16(Xh @ Wkqvh^T + bkqv)   8192x3072
//  G2 (8-phase 256x256): S[b] = Qh@Kh^T * 1/32, mask, skip masked col-tiles
//  SM:  masked row softmax -> attn f16
//  G4 (2-phase 128x128): out2h = f16(perm(attn @ V)), K <= ceil(vlen/32)
//  G5 (2-phase 128x128): out = out2h @ Wprojh^T + bproj (f32)
//
// 8-phase stage discipline (race-free by construction):
//   region re-staged only in a phase STRICTLY AFTER its last-read phase
//   (reads complete before each phase's end barrier via lgkmcnt(0)+MFMA).
//   Per block t (slot s): P1 rd af0+bf01, stage B(sn,h1,t+1)
//                         P2 rd af1,      stage B(sn,h0,t+1)
//                         P3 rd bf23,     stage A(s,h0,t+2)   [A reads ended P2]
//                         P4 (no reads),  stage A(s,h1,t+2)
//   boundary vmcnt(4): drains A+B of t+1, keeps A(t+2) halves in flight.

typedef _Float16 f16;
typedef _Float16 f16x8 __attribute__((ext_vector_type(8)));
typedef float f32x4 __attribute__((ext_vector_type(4)));

__device__ __forceinline__ void gload16(const f16* g, f16* l) {
  __builtin_amdgcn_global_load_lds(
      (const __attribute__((address_space(1))) unsigned int*)g,
      (__attribute__((address_space(3))) unsigned int*)l, 16, 0, 0);
}

#define BARX() __builtin_amdgcn_s_barrier()
#define LGKM0()                                        \
  {                                                    \
    asm volatile("s_waitcnt lgkmcnt(0)" ::: "memory"); \
    __builtin_amdgcn_sched_barrier(0);                 \
  }
#define ASM_VMCNT(N)                                      \
  {                                                       \
    asm volatile("s_waitcnt vmcnt(" #N ")" ::: "memory"); \
    __builtin_amdgcn_sched_barrier(0);                    \
  }

// ================== 8-phase 256x256 kernel (G1, G2) ==================
template <bool MASK, bool BIAS, bool OUTF16>
__global__ __launch_bounds__(512, 2) void gemm8f(
    const f16* __restrict__ A, long lda, const f16* __restrict__ Bp, long ldb,
    void* __restrict__ Cv, long ldc, const float* __restrict__ bias,
    const int* __restrict__ valid_lens, float scale, int K, long strideA,
    long strideB, long strideC) {
  __shared__ __align__(16) f16 As[32768];
  __shared__ __align__(16) f16 Bs[32768];

  const int tid = threadIdx.x;
  const int w = tid >> 6;
  const int ln = tid & 63;
  const int bz = blockIdx.z;

  // XCD-aware bijective swizzle (m204)
  const int gx = gridDim.x, nwg = gx * gridDim.y;
  int lin = blockIdx.y * gx + blockIdx.x;
  {
    const int xcd = lin & 7, rest = lin >> 3;
    const int q = nwg >> 3, r = nwg & 7;
    lin = ((xcd < r) ? xcd * (q + 1) : r * (q + 1) + (xcd - r) * q) + rest;
  }
  const int n0 = (lin % gx) * 256;
  const int m0 = (lin / gx) * 256;

  const int vlen = MASK ? valid_lens[bz] : 0;
  if (MASK && n0 >= vlen) return;

  A += (long)bz * strideA;
  Bp += (long)bz * strideB;

  const int nk = K >> 6;

  const int lq = ln >> 4, lc = ln & 15;
  const int ahalf = w >> 2;              // A half this wave reads
  const int bhalf = (w & 3) >> 1;        // B half this wave reads
  const int bcol0 = ((w & 3) & 1) * 64;  // col offset within B half
  const int wn = (w & 3) * 64;

  f16x8 af0[4][2], af1[4][2], bf[2][2];
  f32x4 acc[8][4];
#pragma unroll
  for (int i = 0; i < 8; ++i)
#pragma unroll
    for (int j = 0; j < 4; ++j) acc[i][j] = (f32x4){0.f, 0.f, 0.f, 0.f};

  auto stA = [&](int slot, int half, int t) {
    const int kt = t << 6;
#pragma unroll
    for (int c = 0; c < 2; ++c)
      gload16(A + (long)(m0 + half * 128 + c * 64 + ln) * lda + kt + w * 8,
              &As[slot * 16384 + half * 8192 + w * 1024 + c * 512]);
  };
  auto stB = [&](int slot, int half, int t) {
    const int kt = t << 6;
#pragma unroll
    for (int c = 0; c < 2; ++c)
      gload16(Bp + (long)(n0 + half * 128 + c * 64 + ln) * ldb + kt + w * 8,
              &Bs[slot * 16384 + half * 8192 + w * 1024 + c * 512]);
  };
  auto rdA0 = [&](int slot) {
#pragma unroll
    for (int i = 0; i < 4; ++i)
#pragma unroll
      for (int ks = 0; ks < 2; ++ks)
        af0[i][ks] =
            *(const f16x8*)&As[slot * 16384 + ahalf * 8192 +
                               (ks * 4 + lq) * 1024 + (i * 16 + lc) * 8];
  };
  auto rdA1 = [&](int slot) {
#pragma unroll
    for (int i = 0; i < 4; ++i)
#pragma unroll
      for (int ks = 0; ks < 2; ++ks)
        af1[i][ks] =
            *(const f16x8*)&As[slot * 16384 + ahalf * 8192 +
                               (ks * 4 + lq) * 1024 + ((i + 4) * 16 + lc) * 8];
  };
  auto rdB = [&](int slot, int qj) {
#pragma unroll
    for (int j = 0; j < 2; ++j)
#pragma unroll
      for (int ks = 0; ks < 2; ++ks)
        bf[j][ks] = *(const f16x8*)&Bs[slot * 16384 + bhalf * 8192 +
                                       (ks * 4 + lq) * 1024 +
                                       (bcol0 + (qj * 2 + j) * 16 + lc) * 8];
  };

#define QMFMA(AF, RB, C0)                                                  \
  _Pragma("unroll") for (int i_ = 0; i_ < 4; ++i_)                         \
      _Pragma("unroll") for (int j_ = 0; j_ < 2; ++j_)                     \
          _Pragma("unroll") for (int ks_ = 0; ks_ < 2; ++ks_)              \
              acc[(RB) + i_][(C0) + j_] =                                  \
                  __builtin_amdgcn_mfma_f32_16x16x32_f16(                  \
                      AF[i_][ks_], bf[j_][ks_], acc[(RB) + i_][(C0) + j_], \
                      0, 0, 0);

  // ---- prologue: tile0 full (4 halves) + A halves of tile1; vmcnt(4) ----
  stA(0, 0, 0); stA(0, 1, 0); stB(0, 0, 0); stB(0, 1, 0);
  if (nk > 1) {
    stA(1, 0, 1); stA(1, 1, 1);
    ASM_VMCNT(4);
  } else {
    ASM_VMCNT(0);
  }
  BARX();

  // ---- main loop: 4 phases per K-tile block ----
  for (int t = 0; t < nk; ++t) {
    const int s = t & 1;
    const int sn = s ^ 1;
    const bool p1 = (t + 1) < nk;
    const bool p2 = (t + 2) < nk;

    // P1: rd af0 (rows 0-3) + bf cols 0-1; stage B(sn,h1,t+1)
    rdA0(s);
    rdB(s, 0);
    if (p1) stB(sn, 1, t + 1);
    BARX(); LGKM0();
    __builtin_amdgcn_s_setprio(1); QMFMA(af0, 0, 0); __builtin_amdgcn_s_setprio(0);
    BARX();

    // P2: rd af1 (rows 4-7); stage B(sn,h0,t+1)
    rdA1(s);
    if (p1) stB(sn, 0, t + 1);
    BARX(); LGKM0();
    __builtin_amdgcn_s_setprio(1); QMFMA(af1, 4, 0); __builtin_amdgcn_s_setprio(0);
    BARX();

    // P3: rd bf cols 2-3; stage A(s,h0,t+2)  [A slot-s reads ended at P2]
    rdB(s, 1);
    if (p2) stA(s, 0, t + 2);
    BARX(); LGKM0();
    __builtin_amdgcn_s_setprio(1); QMFMA(af1, 4, 2); __builtin_amdgcn_s_setprio(0);
    BARX();

    // P4: no reads; stage A(s,h1,t+2); boundary vmcnt
    if (p2) stA(s, 1, t + 2);
    BARX(); LGKM0();
    __builtin_amdgcn_s_setprio(1); QMFMA(af0, 0, 2); __builtin_amdgcn_s_setprio(0);
    if (p2) { ASM_VMCNT(4); } else { ASM_VMCNT(0); }
    BARX();
  }

  // ---- epilogue (C/D: col = ln&15, row = (ln>>4)*4 + r) ----
  const int wm = ahalf * 128;
#pragma unroll
  for (int i = 0; i < 8; ++i) {
#pragma unroll
    for (int j = 0; j < 4; ++j) {
      const int col = n0 + wn + j * 16 + lc;
      const float bv = BIAS ? bias[col] : 0.f;
#pragma unroll
      for (int r = 0; r < 4; ++r) {
        const int row = m0 + wm + i * 16 + lq * 4 + r;
        float c = acc[i][j][r];
        if (MASK) c = (col >= vlen) ? -1000000.0f : c * scale;
        if (BIAS) c += bv;
        const long idx = (long)bz * strideC + (long)row * ldc + col;
        if constexpr (OUTF16)
          ((f16*)Cv)[idx] = (f16)c;
        else
          ((float*)Cv)[idx] = c;
      }
    }
  }
#undef QMFMA
}

// ================== 2-phase 128x128 kernel (G4, G5) ==================
#define BM 128
#define BN 128
#define BK 32

template <bool BT, bool BIAS, bool MASK, bool PERM, bool OUTF16, bool KLIM>
__global__ __launch_bounds__(256) void mfma_gemm(
    const f16* __restrict__ A, long lda, const f16* __restrict__ B, long ldb,
    void* __restrict__ Cv, long ldc, const float* __restrict__ bias,
    const int* __restrict__ valid_lens, float scale, int K, long strideA,
    long strideB, long strideC) {
  __shared__ __align__(16) f16 As[2][BM * BK];
  __shared__ __align__(16) f16 Bs[2][BN * BK];

  const int tid = threadIdx.x;
  const int w = tid >> 6;
  const int ln = tid & 63;
  const int m0 = blockIdx.y * BM;
  const int n0 = blockIdx.x * BN;
  const int bz = blockIdx.z;

  const int vlen = (MASK || KLIM) ? valid_lens[bz] : 0;
  if (MASK && n0 >= vlen) return;

  A += (long)bz * strideA;
  B += (long)bz * strideB;

  int nk = K >> 5;
  if (KLIM) {
    int t = (vlen + BK - 1) >> 5;
    nk = t < nk ? t : nk;
  }

  const int kp = tid & 15;  // k-pair index
  const int dg = tid >> 4;  // d-group (8 cols)

  f32x4 acc[4][4];
#pragma unroll
  for (int i = 0; i < 4; ++i)
#pragma unroll
    for (int j = 0; j < 4; ++j) acc[i][j] = (f32x4){0.f, 0.f, 0.f, 0.f};

  uint4 va, vb2;

  auto stageA = [&](int buf, int kk) {
#pragma unroll
    for (int r = 0; r < 2; ++r)
      gload16(A + (long)(m0 + r * 64 + w * 16 + (ln >> 2)) * lda + kk +
                  (ln & 3) * 8,
              &As[buf][(r * 64 + w * 16) * BK]);
  };
  auto stageB = [&](int buf, int kk) {
#pragma unroll
    for (int r = 0; r < 2; ++r)
      gload16(B + (long)(n0 + r * 64 + w * 16 + (ln >> 2)) * ldb + kk +
                  (ln & 3) * 8,
              &Bs[buf][(r * 64 + w * 16) * BK]);
  };
  auto loadV = [&](int kk) {
    const f16* p = B + (long)(kk + 2 * kp) * ldb + n0 + dg * 8;
    va = *(const uint4*)p;
    vb2 = *(const uint4*)(p + ldb);
  };
  auto writeV = [&](int buf) {
    unsigned int* bw = (unsigned int*)&Bs[buf][0];
    const unsigned int ax[4] = {va.x, va.y, va.z, va.w};
    const unsigned int bx[4] = {vb2.x, vb2.y, vb2.z, vb2.w};
#pragma unroll
    for (int j = 0; j < 4; ++j) {
      unsigned int lo = (ax[j] & 0xffffu) | (bx[j] << 16);
      unsigned int hi = (ax[j] >> 16) | (bx[j] & 0xffff0000u);
      bw[(dg * 8 + 2 * j) * 16 + kp] = lo;
      bw[(dg * 8 + 2 * j + 1) * 16 + kp] = hi;
    }
  };

  stageA(0, 0);
  if (!BT) {
    stageB(0, 0);
  } else {
    loadV(0);
    writeV(0);
  }
  __syncthreads();

  const int wm = (w >> 1) * 64;
  const int wn = (w & 1) * 64;

  for (int kt = 0; kt < nk; ++kt) {
    const int cur = kt & 1;
    const int nxt = cur ^ 1;
    const bool more = (kt + 1) < nk;
    if (more) {
      stageA(nxt, (kt + 1) << 5);
      if (!BT)
        stageB(nxt, (kt + 1) << 5);
      else
        loadV((kt + 1) << 5);
    }
    f16x8 af[4], bff[4];
#pragma unroll
    for (int i = 0; i < 4; ++i)
      af[i] = *(const f16x8*)&As[cur][(wm + i * 16 + (ln & 15)) * BK +
                                      (ln >> 4) * 8];
#pragma unroll
    for (int j = 0; j < 4; ++j)
      bff[j] = *(const f16x8*)&Bs[cur][(wn + j * 16 + (ln & 15)) * BK +
                                       (ln >> 4) * 8];
#pragma unroll
    for (int i = 0; i < 4; ++i)
#pragma unroll
      for (int j = 0; j < 4; ++j)
        acc[i][j] = __builtin_amdgcn_mfma_f32_16x16x32_f16(af[i], bff[j],
                                                           acc[i][j], 0, 0, 0);
    if (BT && more) writeV(nxt);
    __syncthreads();
  }

  const int lq = ln >> 4;
  const int lc = ln & 15;
#pragma unroll
  for (int i = 0; i < 4; ++i) {
#pragma unroll
    for (int j = 0; j < 4; ++j) {
      const int col = n0 + wn + j * 16 + lc;
      const float bv = BIAS ? bias[col] : 0.0f;
#pragma unroll
      for (int r = 0; r < 4; ++r) {
        const int row = m0 + wm + i * 16 + lq * 4 + r;
        float c = acc[i][j][r];
        if (MASK) c = (col >= vlen) ? -1000000.0f : c * scale;
        if (BIAS) c += bv;
        if (PERM) {
          const long idx =
              ((long)bz * 2048 + 2 * col + (row >> 10)) * 1024 + (row & 1023);
          ((f16*)Cv)[idx] = (f16)c;
        } else {
          const long idx = (long)bz * strideC + (long)row * ldc + col;
          if (OUTF16)
            ((f16*)Cv)[idx] = (f16)c;
          else
            ((float*)Cv)[idx] = c;
        }
      }
    }
  }
}

// ================== softmax + cvt ==================
__global__ __launch_bounds__(256) void softmax_rows(
    const float* __restrict__ S, f16* __restrict__ attn,
    const int* __restrict__ vlens) {
  const long row = blockIdx.x;
  const int b = (int)(row >> 11);
  const int vlen = vlens[b];
  const float* p = S + row * 2048;
  const int tid = threadIdx.x;
  const int wave = tid >> 6, lane = tid & 63;
  const int c0 = tid * 8;

  float v[8];
  if (c0 + 8 <= vlen) {
    const float4 a = *(const float4*)(p + c0);
    const float4 bq = *(const float4*)(p + c0 + 4);
    v[0] = a.x; v[1] = a.y; v[2] = a.z; v[3] = a.w;
    v[4] = bq.x; v[5] = bq.y; v[6] = bq.z; v[7] = bq.w;
  } else {
#pragma unroll
    for (int j = 0; j < 8; ++j)
      v[j] = (c0 + j < vlen) ? p[c0 + j] : -1000000.0f;
  }

  float mx = v[0];
#pragma unroll
  for (int j = 1; j < 8; ++j) mx = fmaxf(mx, v[j]);
#pragma unroll
  for (int o = 1; o < 64; o <<= 1) mx = fmaxf(mx, __shfl_xor(mx, o));
  __shared__ float redm[4];
  if (lane == 0) redm[wave] = mx;
  __syncthreads();
  mx = fmaxf(fmaxf(redm[0], redm[1]), fmaxf(redm[2], redm[3]));

  float s = 0.f;
#pragma unroll
  for (int j = 0; j < 8; ++j) {
    v[j] = __expf(v[j] - mx);
    s += v[j];
  }
#pragma unroll
  for (int o = 1; o < 64; o <<= 1) s += __shfl_xor(s, o);
  __shared__ float reds[4];
  if (lane == 0) reds[wave] = s;
  __syncthreads();
  s = reds[0] + reds[1] + reds[2] + reds[3];

  const float inv = 1.0f / s;
  f16x8 ov;
#pragma unroll
  for (int j = 0; j < 8; ++j) ov[j] = (f16)(v[j] * inv);
  *(f16x8*)(attn + row * 2048 + c0) = ov;
}

__global__ __launch_bounds__(256) void cvt_f32_f16(const float* __restrict__ s,
                                                   f16* __restrict__ d, int n) {
  const int i = (blockIdx.x * 256 + threadIdx.x) * 8;
  if (i >= n) return;
  const float4 a = *(const float4*)(s + i);
  const float4 b = *(const float4*)(s + i + 4);
  f16x8 o;
  o[0] = (f16)a.x; o[1] = (f16)a.y; o[2] = (f16)a.z; o[3] = (f16)a.w;
  o[4] = (f16)b.x; o[5] = (f16)b.y; o[6] = (f16)b.z; o[7] = (f16)b.w;
  *(f16x8*)(d + i) = o;
}

extern "C" void kernel_launch(void* const* d_in, const int* in_sizes, int n_in,
                              void* d_out, int out_size, void* d_ws,
                              size_t ws_size, hipStream_t stream) {
  const float* X = (const float*)d_in[0];
  const int* vlens = (const int*)d_in[1];
  const float* Wkqv = (const float*)d_in[2];
  const float* bkqv = (const float*)d_in[3];
  const float* Wproj = (const float*)d_in[4];
  const float* bproj = (const float*)d_in[5];
  float* out = (float*)d_out;

  char* w = (char*)d_ws;
  f16* Xh = (f16*)w;      w += 8192L * 1024 * 2;
  f16* Wkqvh = (f16*)w;   w += 3072L * 1024 * 2;
  f16* Wprojh = (f16*)w;  w += 1024L * 1024 * 2;
  f16* kqvh = (f16*)w;    w += 8192L * 3072 * 2;
  f16* attnh = (f16*)w;   w += 4L * 2048 * 2048 * 2;
  f16* out2h = (f16*)w;   w += 8192L * 1024 * 2;
  float* S = (float*)w;

  cvt_f32_f16<<<4096, 256, 0, stream>>>(X, Xh, 8192 * 1024);
  cvt_f32_f16<<<1536, 256, 0, stream>>>(Wkqv, Wkqvh, 3072 * 1024);
  cvt_f32_f16<<<512, 256, 0, stream>>>(Wproj, Wprojh, 1024 * 1024);

  // G1: kqvh = f16(Xh @ Wkqvh^T + bkqv)   M=8192 N=3072 K=1024
  gemm8f<false, true, true><<<dim3(12, 32, 1), 512, 0, stream>>>(
      Xh, 1024, Wkqvh, 1024, kqvh, 3072, bkqv, nullptr, 1.0f, 1024, 0, 0, 0);

  // G2: S[b] = Qh @ Kh^T * 1/32, masked   M=N=2048 K=1024
  gemm8f<true, false, false><<<dim3(8, 8, 4), 512, 0, stream>>>(
      kqvh + 1024, 3072, kqvh, 3072, S, 2048, nullptr, vlens, 0.03125f, 1024,
      2048L * 3072, 2048L * 3072, 2048L * 2048);

  // SM: masked softmax rows -> fp16 attn
  softmax_rows<<<8192, 256, 0, stream>>>(S, attnh, vlens);

  // G4: out2h = f16(perm(attn @ V))   M=2048 N=1024 K<=2048 (vlen-limited)
  mfma_gemm<true, false, false, true, true, true>
      <<<dim3(8, 16, 4), 256, 0, stream>>>(
          attnh, 2048, kqvh + 2048, 3072, out2h, 1024, nullptr, vlens, 1.0f,
          2048, 2048L * 2048, 2048L * 3072, 2048L * 1024);

  // G5: out = out2h @ Wprojh^T + bproj   M=8192 N=1024 K=1024 (f32 out)
  mfma_gemm<false, true, false, false, false, false>
      <<<dim3(8, 64, 1), 256, 0, stream>>>(out2h, 1024, Wprojh, 1024, out,
                                           1024, bproj, nullptr, 1.0f, 1024, 0,
                                           0, 0);
}